// Round 1
// baseline (351.268 us; speedup 1.0000x reference)
//
#include <hip/hip_runtime.h>

#define EPS 1e-10f
#define FAR_DELTA 1e10f

// DPP move within 16-lane rows: out-of-bounds source lanes yield `old`.
// CTRL: row_shl:N = 0x100+N, row_shr:N = 0x110+N, row_ror:N = 0x120+N.
template<int CTRL>
__device__ __forceinline__ float dpp_mov(float x, float old) {
    return __int_as_float(__builtin_amdgcn_update_dpp(
        __float_as_int(old), __float_as_int(x), CTRL, 0xF, 0xF, false));
}

// One ray per 16-lane group (4 rays per wave). Each lane holds 8 consecutive
// samples. ALL cross-lane traffic is DPP row ops (VALU-speed, no LDS pipe):
//   seam        : row_shl:1
//   scan        : row_shr:{1,2,4,8} (old=1.0 gives the product identity)
//   reduction   : row_ror:{8,4,2,1} rotations (every lane ends with the total)
// All 10 global dwordx4 loads are issued up front -> one memory-latency
// exposure with full MLP instead of two register-starved phases.
__global__ __launch_bounds__(256) void volrend_kernel(
    const float* __restrict__ density,   // [N,128]
    const float* __restrict__ feature,   // [N,128,3]
    const float* __restrict__ depth,     // [N,128]
    float* __restrict__ feat_out,        // [N,3]
    float* __restrict__ depth_out,       // [N]
    int N)
{
    const int tid  = threadIdx.x;
    const int lane = tid & 63;
    const int wv   = tid >> 6;        // wave within block (0..3)
    const int j    = lane & 15;       // sublane within ray group
    const int sub  = lane >> 4;       // ray slot within wave (0..3)
    const int ray  = blockIdx.x * 16 + wv * 4 + sub;
    if (ray >= N) return;

    // Per-lane bases: 8 samples starting at j*8. All 16B-aligned.
    const float4* d4 = (const float4*)(density + (size_t)ray * 128 + j * 8);
    const float4* z4 = (const float4*)(depth   + (size_t)ray * 128 + j * 8);
    const float4* f4 = (const float4*)(feature + (size_t)ray * 384 + j * 24);

    // ---- Issue ALL loads now (10x dwordx4 in flight). ----
    float4 dA = d4[0], dB = d4[1];
    float4 zA = z4[0], zB = z4[1];
    float4 F0 = f4[0], F1 = f4[1], F2 = f4[2], F3 = f4[3], F4 = f4[4], F5 = f4[5];

    float z[8]  = {zA.x, zA.y, zA.z, zA.w, zB.x, zB.y, zB.z, zB.w};
    float dn[8] = {dA.x, dA.y, dA.z, dA.w, dB.x, dB.y, dB.z, dB.w};

    // Next sublane's first depth (seam delta). j==15 overrides with FAR.
    float znext = dpp_mov<0x101>(z[0], 0.0f);   // row_shl:1

    float al[8], tt[8];
    #pragma unroll
    for (int k = 0; k < 8; ++k) {
        float delta = (k < 7) ? (z[k + 1] - z[k])
                              : ((j == 15) ? FAR_DELTA : (znext - z[7]));
        float ex = __expf(-fmaxf(dn[k], 0.0f) * delta); // = 1 - alpha
        al[k] = 1.0f - ex;          // alpha
        tt[k] = ex + EPS;           // cumprod term (1 - alpha + eps)
    }

    // Lane-local inclusive product of the 8 terms.
    float loc = tt[0];
    #pragma unroll
    for (int k = 1; k < 8; ++k) loc *= tt[k];

    // Width-16 inclusive product scan, pure DPP (invalid lanes read 1.0).
    float s = loc;
    s *= dpp_mov<0x111>(s, 1.0f);   // row_shr:1
    s *= dpp_mov<0x112>(s, 1.0f);   // row_shr:2
    s *= dpp_mov<0x114>(s, 1.0f);   // row_shr:4
    s *= dpp_mov<0x118>(s, 1.0f);   // row_shr:8
    float excl = dpp_mov<0x111>(s, 1.0f);  // exclusive shift; lane0 -> 1.0

    float f[24] = {F0.x, F0.y, F0.z, F0.w, F1.x, F1.y, F1.z, F1.w,
                   F2.x, F2.y, F2.z, F2.w, F3.x, F3.y, F3.z, F3.w,
                   F4.x, F4.y, F4.z, F4.w, F5.x, F5.y, F5.z, F5.w};

    // Serial weights + accumulate (lane-local, good ILP).
    float trans = excl;
    float a0 = 0.0f, a1 = 0.0f, a2 = 0.0f, ad = 0.0f;
    #pragma unroll
    for (int k = 0; k < 8; ++k) {
        float wk = al[k] * trans;
        trans *= tt[k];
        a0 += wk * f[3 * k + 0];
        a1 += wk * f[3 * k + 1];
        a2 += wk * f[3 * k + 2];
        ad += wk * z[k];
    }

    // Width-16 sum reduction via row rotations (4 parallel VALU chains).
    a0 += dpp_mov<0x128>(a0, 0.0f);  // ror:8
    a1 += dpp_mov<0x128>(a1, 0.0f);
    a2 += dpp_mov<0x128>(a2, 0.0f);
    ad += dpp_mov<0x128>(ad, 0.0f);
    a0 += dpp_mov<0x124>(a0, 0.0f);  // ror:4
    a1 += dpp_mov<0x124>(a1, 0.0f);
    a2 += dpp_mov<0x124>(a2, 0.0f);
    ad += dpp_mov<0x124>(ad, 0.0f);
    a0 += dpp_mov<0x122>(a0, 0.0f);  // ror:2
    a1 += dpp_mov<0x122>(a1, 0.0f);
    a2 += dpp_mov<0x122>(a2, 0.0f);
    ad += dpp_mov<0x122>(ad, 0.0f);
    a0 += dpp_mov<0x121>(a0, 0.0f);  // ror:1
    a1 += dpp_mov<0x121>(a1, 0.0f);
    a2 += dpp_mov<0x121>(a2, 0.0f);
    ad += dpp_mov<0x121>(ad, 0.0f);

    if (j == 0) {
        feat_out[(size_t)ray * 3 + 0] = a0;
        feat_out[(size_t)ray * 3 + 1] = a1;
        feat_out[(size_t)ray * 3 + 2] = a2;
        depth_out[ray] = ad;
    }
}

extern "C" void kernel_launch(void* const* d_in, const int* in_sizes, int n_in,
                              void* d_out, int out_size, void* d_ws, size_t ws_size,
                              hipStream_t stream) {
    const float* density = (const float*)d_in[0];   // [N,128]
    const float* feature = (const float*)d_in[1];   // [N,128,3]
    const float* depth   = (const float*)d_in[2];   // [N,128]

    const int P = 128;
    const int N = in_sizes[0] / P;                  // 131072

    float* feat_out  = (float*)d_out;                 // [N,3]
    float* depth_out = (float*)d_out + (size_t)N * 3; // [N]

    // 16 rays per block (4 waves x 4 rays).
    dim3 grid((N + 15) / 16);
    dim3 block(256);
    volrend_kernel<<<grid, block, 0, stream>>>(density, feature, depth,
                                               feat_out, depth_out, N);
}